// Round 3
// baseline (613.443 us; speedup 1.0000x reference)
//
#include <hip/hip_runtime.h>
#include <math.h>

#define NN 100000
#define DF 512
#define HID 16
#define NBUCK 392            // ceil(NN/256) buckets of 256 dst values
#define EPB 4096             // edges per block in bucketA (256 thr x 16)
#define BCAP 7800            // bucketB LDS staging capacity (62.4 KB)

#define TN 128               // gemm1: nodes per block
#define KC 64                // gemm1: k-chunk (floats)
#define NCH (DF / KC)        // 8 chunks
#define LROW 65              // padded LDS row stride (floats)

// Flag: 1 if edge_index is int64-laid-out, 0 if int32.
__device__ int g_idx64;

__global__ void detect_idx_kernel(const long long* __restrict__ idx) {
    int lane = threadIdx.x;  // 64 threads
    int ok = 1;
    for (int i = lane; i < 128; i += 64) {
        long long v = idx[i];
        if (v < 0 || v >= NN) ok = 0;
    }
    unsigned long long m = __ballot(ok);
    if (lane == 0) g_idx64 = (m == ~0ULL);
}

// ---------------- GEMM1: h1 = x @ W1, LDS-transposed staging ---------------
// 256 threads / 128-node tile. Staging: lanes read 256B-contiguous row chunks
// (coalesced), write to +1-padded LDS rows (2-way banks = free). Compute:
// thread-per-node from LDS with wave-uniform k so W1 stays on the scalar
// path. Split-K x2 across wave pairs (half = tid>>7, wave-uniform), LDS
// combine. Next chunk's loads issued before compute -> latency hidden.
__global__ __launch_bounds__(256) void gemm1_kernel(
    const float* __restrict__ x, const float* __restrict__ W1,
    float* __restrict__ h1, int nN)
{
    __shared__ float sx[TN * LROW];      // 33.3 KB
    __shared__ float part[TN * 17];      // 8.7 KB
    const int t = threadIdx.x;
    const int tr = t >> 4;               // 0..15 (row-in-group for staging)
    const int tq = t & 15;               // 0..15 (float4 col for staging)
    const int node0 = blockIdx.x * TN;
    const int node = t & (TN - 1);
    const int half = t >> 7;             // wave-uniform: waves 0,1 -> 0; 2,3 -> 1

    const float4* x4 = (const float4*)x;
    int rowg[8];
#pragma unroll
    for (int i = 0; i < 8; ++i) {
        int r = node0 + i * 16 + tr;
        rowg[i] = (r < nN) ? r : (nN - 1);   // clamp: duplicate loads, harmless
    }

    // prefetch chunk 0
    float4 pf[8];
#pragma unroll
    for (int i = 0; i < 8; ++i)
        pf[i] = x4[(size_t)rowg[i] * (DF / 4) + tq];

    float acc[16];
#pragma unroll
    for (int c = 0; c < 16; ++c) acc[c] = 0.f;

    for (int kc = 0; kc < NCH; ++kc) {
        // stage chunk kc into LDS (compiler waits vmcnt on pf use)
#pragma unroll
        for (int i = 0; i < 8; ++i) {
            int a = (i * 16 + tr) * LROW + tq * 4;
            sx[a + 0] = pf[i].x; sx[a + 1] = pf[i].y;
            sx[a + 2] = pf[i].z; sx[a + 3] = pf[i].w;
        }
        __syncthreads();
        // issue next chunk's loads; they fly during compute
        if (kc + 1 < NCH) {
            int qb = (kc + 1) * 16 + tq;
#pragma unroll
            for (int i = 0; i < 8; ++i)
                pf[i] = x4[(size_t)rowg[i] * (DF / 4) + qb];
        }
        const float* wb = W1 + (kc * KC + half * 32) * HID;  // wave-uniform
        const float* xr = sx + node * LROW + half * 32;
#pragma unroll 8
        for (int kk = 0; kk < 32; ++kk) {
            float s = xr[kk];
            const float* wr = wb + kk * HID;
#pragma unroll
            for (int c = 0; c < 16; ++c)
                acc[c] = fmaf(s, wr[c], acc[c]);
        }
        __syncthreads();
    }

    // combine split-K halves through LDS
    if (half == 1) {
#pragma unroll
        for (int c = 0; c < 16; ++c) part[node * 17 + c] = acc[c];
    }
    __syncthreads();
    if (half == 0) {
        int gn = node0 + node;
        if (gn < nN) {
#pragma unroll
            for (int c = 0; c < 16; ++c) acc[c] += part[node * 17 + c];
            float4* o = (float4*)(h1 + (size_t)gn * HID);
#pragma unroll
            for (int g = 0; g < 4; ++g)
                o[g] = make_float4(acc[g * 4 + 0], acc[g * 4 + 1],
                                   acc[g * 4 + 2], acc[g * 4 + 3]);
        }
    }
}

// ---------------- Bucket-level histogram (LDS-first, 2 edges/iter) ---------
__global__ __launch_bounds__(256) void bucket_hist_kernel(
    const void* __restrict__ eidx, int* __restrict__ bcnt, int nE)
{
    __shared__ int h[NBUCK];
    for (int i = threadIdx.x; i < NBUCK; i += 256) h[i] = 0;
    __syncthreads();
    const int i64 = g_idx64;
    int stride = gridDim.x * 256;
    int tid = blockIdx.x * 256 + threadIdx.x;
    if ((nE & 1) == 0) {
        int nE2 = nE >> 1;
        if (i64) {
            const int4* dp = (const int4*)((const long long*)eidx + nE);
            for (int i = tid; i < nE2; i += stride) {
                int4 d = dp[i];
                if (d.y == 0 && (unsigned)d.x < (unsigned)NN) atomicAdd(&h[d.x >> 8], 1);
                if (d.w == 0 && (unsigned)d.z < (unsigned)NN) atomicAdd(&h[d.z >> 8], 1);
            }
        } else {
            const int2* dp = (const int2*)((const int*)eidx + nE);
            for (int i = tid; i < nE2; i += stride) {
                int2 d = dp[i];
                if ((unsigned)d.x < (unsigned)NN) atomicAdd(&h[d.x >> 8], 1);
                if ((unsigned)d.y < (unsigned)NN) atomicAdd(&h[d.y >> 8], 1);
            }
        }
    } else {
        for (int e = tid; e < nE; e += stride) {
            int d;
            if (i64) d = (int)((const long long*)eidx)[nE + e];
            else     d = ((const int*)eidx)[nE + e];
            if ((unsigned)d < (unsigned)NN) atomicAdd(&h[d >> 8], 1);
        }
    }
    __syncthreads();
    for (int i = threadIdx.x; i < NBUCK; i += 256)
        if (h[i]) atomicAdd(&bcnt[i], h[i]);
}

// ---------------- Scan of 392 bucket counts -> bbase / cursor --------------
__global__ __launch_bounds__(512) void bucket_scan_kernel(
    const int* __restrict__ bcnt, int* __restrict__ bbase,
    int* __restrict__ cursor, int* __restrict__ rowStart)
{
    __shared__ int s[512];
    int t = threadIdx.x;
    int v = (t < NBUCK) ? bcnt[t] : 0;
    s[t] = v;
    __syncthreads();
    for (int off = 1; off < 512; off <<= 1) {
        int u = (t >= off) ? s[t - off] : 0;
        __syncthreads();
        s[t] += u;
        __syncthreads();
    }
    int excl = s[t] - v;   // exclusive prefix
    if (t < NBUCK) { bbase[t] = excl; cursor[t] = excl; }
    if (t == NBUCK) bbase[t] = excl;          // == total
    if (t == NBUCK) rowStart[NN] = excl;
}

// ---------------- Pass A: coarse bucket sort -------------------------------
__global__ __launch_bounds__(256) void bucketA_kernel(
    const void* __restrict__ eidx, const float* __restrict__ ew,
    int* __restrict__ cursor, int2* __restrict__ packed, int nE)
{
    __shared__ int cnt[NBUCK];
    __shared__ int base[NBUCK];
    int t = threadIdx.x;
    for (int i = t; i < NBUCK; i += 256) cnt[i] = 0;
    __syncthreads();

    const int e0 = blockIdx.x * EPB;
    const int i64 = g_idx64;
    int lo[16]; float wv[16]; int bk[16];
#pragma unroll
    for (int i = 0; i < 16; ++i) {
        int e = e0 + t + i * 256;
        bk[i] = -1;
        if (e < nE) {
            int s, d;
            if (i64) {
                const long long* p = (const long long*)eidx;
                s = (int)p[e]; d = (int)p[nE + e];
            } else {
                const int* p = (const int*)eidx;
                s = p[e]; d = p[nE + e];
            }
            if ((unsigned)d < (unsigned)NN) {
                float w = ew[e];
                if ((unsigned)s >= (unsigned)NN) { s = 0; w = 0.f; }
                bk[i] = d >> 8;
                lo[i] = s | ((d & 255) << 20);
                wv[i] = w;
                atomicAdd(&cnt[bk[i]], 1);
            }
        }
    }
    __syncthreads();
    for (int i = t; i < NBUCK; i += 256)
        base[i] = (cnt[i] > 0) ? atomicAdd(&cursor[i], cnt[i]) : 0;
    __syncthreads();
    for (int i = t; i < NBUCK; i += 256) cnt[i] = 0;
    __syncthreads();
#pragma unroll
    for (int i = 0; i < 16; ++i) {
        if (bk[i] >= 0) {
            int r = atomicAdd(&cnt[bk[i]], 1);
            packed[base[bk[i]] + r] = make_int2(lo[i], __float_as_int(wv[i]));
        }
    }
}

// ---------------- Pass B: per-bucket fine CSR, single global read ----------
__global__ __launch_bounds__(256) void bucketB_kernel(
    const int2* __restrict__ packed, const int* __restrict__ bbase,
    int* __restrict__ rowStart, int2* __restrict__ se, int nN)
{
    __shared__ int hcnt[256];
    __shared__ int wtot[4];
    __shared__ int2 stage[BCAP];
    int b = blockIdx.x;
    int t = threadIdx.x;
    int beg = bbase[b], end = bbase[b + 1];
    int cnt = end - beg;

    hcnt[t] = 0;
    __syncthreads();
    for (int i = t; i < cnt; i += 256) {
        int2 e = packed[beg + i];
        if (i < BCAP) stage[i] = e;
        atomicAdd(&hcnt[(e.x >> 20) & 255], 1);
    }
    __syncthreads();

    // exclusive scan of hcnt[256]: shfl within waves + wave offsets
    int v = hcnt[t];
    int incl = v;
#pragma unroll
    for (int off = 1; off < 64; off <<= 1) {
        int u = __shfl_up(incl, off, 64);
        if ((t & 63) >= off) incl += u;
    }
    if ((t & 63) == 63) wtot[t >> 6] = incl;
    __syncthreads();
    int woff = 0;
#pragma unroll
    for (int w = 0; w < 4; ++w) if (w < (t >> 6)) woff += wtot[w];
    int excl = incl - v + woff;

    int node = b * 256 + t;
    if (node < nN) rowStart[node] = beg + excl;
    __syncthreads();
    hcnt[t] = beg + excl;   // reuse as cursor
    __syncthreads();

    for (int i = t; i < cnt; i += 256) {
        int2 e = (i < BCAP) ? stage[i] : packed[beg + i];
        int dl = (e.x >> 20) & 255;
        int pos = atomicAdd(&hcnt[dl], 1);
        se[pos] = make_int2(e.x & 0xFFFFF, e.y);
    }
}

// ---------------- Fused aggregation ----------------------------------------
// agg[n] = sum_e w_e * h[src_e]; 4 threads per node (one float4 slice each).
// EPI==0: epilogue h2 = relu(agg + b1) @ Wn   (full 16-vec via quad shuffles)
// EPI==1: epilogue out = log_softmax(agg + b2)
template <int EPI>
__global__ __launch_bounds__(256) void gather_fused_kernel(
    const int* __restrict__ rowStart, const int2* __restrict__ se,
    const float* __restrict__ h, const float* __restrict__ bias,
    const float* __restrict__ Wn, float* __restrict__ outp, int nN)
{
    __shared__ float sW[256];
    __shared__ float sb[16];
    if (EPI == 0) sW[threadIdx.x] = Wn[threadIdx.x];
    if (threadIdx.x < 16) sb[threadIdx.x] = bias[threadIdx.x];
    __syncthreads();

    int t = blockIdx.x * 256 + threadIdx.x;
    int n = t >> 2;
    if (n >= nN) return;          // quad-uniform: n identical across the quad
    int c4 = t & 3;
    int beg = rowStart[n], end = rowStart[n + 1];
    const float4* h4 = (const float4*)h;

    float ax = 0.f, ay = 0.f, az = 0.f, aw = 0.f;
    int p = beg;
    // 4 independent load chains in flight per thread
    for (; p + 4 <= end; p += 4) {
        int2 e0 = se[p], e1 = se[p + 1], e2 = se[p + 2], e3 = se[p + 3];
        float4 v0 = h4[(size_t)(unsigned)e0.x * 4 + c4];
        float4 v1 = h4[(size_t)(unsigned)e1.x * 4 + c4];
        float4 v2 = h4[(size_t)(unsigned)e2.x * 4 + c4];
        float4 v3 = h4[(size_t)(unsigned)e3.x * 4 + c4];
        float w0 = __int_as_float(e0.y), w1 = __int_as_float(e1.y);
        float w2 = __int_as_float(e2.y), w3 = __int_as_float(e3.y);
        ax = fmaf(w0, v0.x, ax); ay = fmaf(w0, v0.y, ay);
        az = fmaf(w0, v0.z, az); aw = fmaf(w0, v0.w, aw);
        ax = fmaf(w1, v1.x, ax); ay = fmaf(w1, v1.y, ay);
        az = fmaf(w1, v1.z, az); aw = fmaf(w1, v1.w, aw);
        ax = fmaf(w2, v2.x, ax); ay = fmaf(w2, v2.y, ay);
        az = fmaf(w2, v2.z, az); aw = fmaf(w2, v2.w, aw);
        ax = fmaf(w3, v3.x, ax); ay = fmaf(w3, v3.y, ay);
        az = fmaf(w3, v3.z, az); aw = fmaf(w3, v3.w, aw);
    }
    for (; p < end; ++p) {
        int2 e = se[p];
        float4 v = h4[(size_t)(unsigned)e.x * 4 + c4];
        float w = __int_as_float(e.y);
        ax = fmaf(w, v.x, ax); ay = fmaf(w, v.y, ay);
        az = fmaf(w, v.z, az); aw = fmaf(w, v.w, aw);
    }

    int lane = threadIdx.x & 63;
    int lb = lane & ~3;           // quad base lane

    if (EPI == 0) {
        float v0 = fmaxf(ax + sb[c4 * 4 + 0], 0.f);
        float v1 = fmaxf(ay + sb[c4 * 4 + 1], 0.f);
        float v2 = fmaxf(az + sb[c4 * 4 + 2], 0.f);
        float v3 = fmaxf(aw + sb[c4 * 4 + 3], 0.f);
        float vk[16];
#pragma unroll
        for (int j = 0; j < 4; ++j) {
            vk[4 * j + 0] = __shfl(v0, lb + j, 64);
            vk[4 * j + 1] = __shfl(v1, lb + j, 64);
            vk[4 * j + 2] = __shfl(v2, lb + j, 64);
            vk[4 * j + 3] = __shfl(v3, lb + j, 64);
        }
        float o0 = 0.f, o1 = 0.f, o2 = 0.f, o3 = 0.f;
#pragma unroll
        for (int k = 0; k < 16; ++k) {
            float s = vk[k];
            o0 = fmaf(s, sW[k * 16 + c4 * 4 + 0], o0);
            o1 = fmaf(s, sW[k * 16 + c4 * 4 + 1], o1);
            o2 = fmaf(s, sW[k * 16 + c4 * 4 + 2], o2);
            o3 = fmaf(s, sW[k * 16 + c4 * 4 + 3], o3);
        }
        ((float4*)outp)[(size_t)n * 4 + c4] = make_float4(o0, o1, o2, o3);
    } else {
        float v0 = ax + sb[c4 * 4 + 0];
        float v1 = ay + sb[c4 * 4 + 1];
        float v2 = az + sb[c4 * 4 + 2];
        float v3 = aw + sb[c4 * 4 + 3];
        float m = fmaxf(fmaxf(v0, v1), fmaxf(v2, v3));
        m = fmaxf(m, __shfl_xor(m, 1, 64));
        m = fmaxf(m, __shfl_xor(m, 2, 64));
        float s = expf(v0 - m) + expf(v1 - m) + expf(v2 - m) + expf(v3 - m);
        s += __shfl_xor(s, 1, 64);
        s += __shfl_xor(s, 2, 64);
        float l = m + logf(s);
        ((float4*)outp)[(size_t)n * 4 + c4] =
            make_float4(v0 - l, v1 - l, v2 - l, v3 - l);
    }
}

extern "C" void kernel_launch(void* const* d_in, const int* in_sizes, int n_in,
                              void* d_out, int out_size, void* d_ws, size_t ws_size,
                              hipStream_t stream)
{
    const float* x  = (const float*)d_in[0];
    const void*  ei = d_in[1];
    const float* ew = (const float*)d_in[2];
    const float* W1 = (const float*)d_in[3];
    const float* b1 = (const float*)d_in[4];
    const float* W2 = (const float*)d_in[5];
    const float* b2 = (const float*)d_in[6];
    float* out = (float*)d_out;

    const int N = NN;
    const int E = in_sizes[2];

    const size_t featB = (size_t)N * HID * sizeof(float);           // 6.4 MB
    const size_t rowB  = (((size_t)(N + 1) * 4) + 255) & ~255ULL;
    const size_t bkB   = (((size_t)(NBUCK + 1) * 4) + 255) & ~255ULL;
    const size_t seB   = ((size_t)E * 8 + 255) & ~255ULL;           // 25.6 MB

    char* w = (char*)d_ws;
    float* buf0 = (float*)w;      w += (featB + 255) & ~255ULL;
    float* buf1 = (float*)w;      w += (featB + 255) & ~255ULL;
    int*   rowStart = (int*)w;    w += rowB;
    int*   bcnt = (int*)w;        w += bkB;
    int*   bbase = (int*)w;       w += bkB;
    int*   cursor = (int*)w;      w += bkB;
    int2*  se = (int2*)w;         w += seB;
    int2*  packed = (int2*)w;     w += seB;

    detect_idx_kernel<<<1, 64, 0, stream>>>((const long long*)ei);
    gemm1_kernel<<<(N + TN - 1) / TN, 256, 0, stream>>>(x, W1, buf0, N);

    const int nblocks4 = (N * 4 + 255) / 256;

    // Bucketed CSR build: LDS-first histogram, tiny scan, per-bucket fine CSR.
    hipMemsetAsync(bcnt, 0, (size_t)NBUCK * 4, stream);
    bucket_hist_kernel<<<256, 256, 0, stream>>>(ei, bcnt, E);
    bucket_scan_kernel<<<1, 512, 0, stream>>>(bcnt, bbase, cursor, rowStart);
    bucketA_kernel<<<(E + EPB - 1) / EPB, 256, 0, stream>>>(ei, ew, cursor, packed, E);
    bucketB_kernel<<<NBUCK, 256, 0, stream>>>(packed, bbase, rowStart, se, N);

    // Fused: gather+transform (h2 = relu(agg1+b1)@W2), gather+log_softmax.
    gather_fused_kernel<0><<<nblocks4, 256, 0, stream>>>(rowStart, se, buf0, b1, W2, buf1, N);
    gather_fused_kernel<1><<<nblocks4, 256, 0, stream>>>(rowStart, se, buf1, b2, W2, out, N);
}

// Round 4
// 507.721 us; speedup vs baseline: 1.2082x; 1.2082x over previous
//
#include <hip/hip_runtime.h>
#include <math.h>

#define NN 100000
#define DF 512
#define HID 16
#define NBUCK 392            // ceil(NN/256) buckets of 256 dst values
#define EPB 4096             // edges per block in bucketA (256 thr x 16)
#define BCAP 7800            // bucketB LDS staging capacity (62.4 KB)

#define TN 256               // gemm1: nodes per block
#define KC 64                // gemm1: k-chunk (floats)
#define NCH (DF / KC)        // 8 chunks
#define LROW 65              // padded LDS row stride (floats): bank = node%32, 2-way = free

// Flag: 1 if edge_index is int64-laid-out, 0 if int32.
__device__ int g_idx64;

__global__ void detect_idx_kernel(const long long* __restrict__ idx) {
    int lane = threadIdx.x;  // 64 threads
    int ok = 1;
    for (int i = lane; i < 128; i += 64) {
        long long v = idx[i];
        if (v < 0 || v >= NN) ok = 0;
    }
    unsigned long long m = __ballot(ok);
    if (lane == 0) g_idx64 = (m == ~0ULL);
}

// ---------------- GEMM1: h1 = x @ W1 ---------------------------------------
// 512 threads / 256-node tile. x staged through LDS with 256B-contiguous
// coalesced loads; +1-padded rows keep compute reads at 2 lanes/bank (free).
// Split-K x2 across wave halves, with hf = readfirstlane(t>>8) so the
// compiler PROVES W1 addresses uniform -> s_load scalar path (the round-1/3
// regression was W1 falling off the scalar path onto per-lane global loads).
__global__ __launch_bounds__(512) void gemm1_kernel(
    const float* __restrict__ x, const float* __restrict__ W1,
    float* __restrict__ h1, int nN)
{
    __shared__ float sx[TN * LROW];      // 66.6 KB; also reused for combine
    const int t = threadIdx.x;
    const int hf = __builtin_amdgcn_readfirstlane(t >> 8);  // waves 0-3: 0, 4-7: 1
    const int node = t & (TN - 1);
    const int node0 = blockIdx.x * TN;
    const int tr = t >> 4;               // 0..31: row-in-pass for staging
    const int tq = t & 15;               // 0..15: float4 col for staging

    const float4* x4 = (const float4*)x;
    int rowg[8];
#pragma unroll
    for (int i = 0; i < 8; ++i) {
        int r = node0 + i * 32 + tr;
        rowg[i] = (r < nN) ? r : (nN - 1);   // clamp: duplicate loads, harmless
    }

    // prefetch chunk 0 (float4 cols [0,16))
    float4 pf[8];
#pragma unroll
    for (int i = 0; i < 8; ++i)
        pf[i] = x4[(size_t)rowg[i] * (DF / 4) + tq];

    float acc[16];
#pragma unroll
    for (int c = 0; c < 16; ++c) acc[c] = 0.f;

    for (int kc = 0; kc < NCH; ++kc) {
        // stage chunk kc into LDS (compiler inserts vmcnt waits on pf use)
#pragma unroll
        for (int i = 0; i < 8; ++i) {
            int a = (i * 32 + tr) * LROW + tq * 4;
            sx[a + 0] = pf[i].x; sx[a + 1] = pf[i].y;
            sx[a + 2] = pf[i].z; sx[a + 3] = pf[i].w;
        }
        __syncthreads();
        // issue next chunk's loads; they fly during compute
        if (kc + 1 < NCH) {
            int qb = (kc + 1) * 16 + tq;
#pragma unroll
            for (int i = 0; i < 8; ++i)
                pf[i] = x4[(size_t)rowg[i] * (DF / 4) + qb];
        }
        // compute: this half's 32 k-values of the staged chunk
        const float* wb = W1 + (kc * KC + hf * 32) * HID;  // uniform -> s_load
        const float* xr = sx + node * LROW + hf * 32;
#pragma unroll 4
        for (int kk = 0; kk < 32; ++kk) {
            float s = xr[kk];
            const float* wr = wb + kk * HID;
#pragma unroll
            for (int c = 0; c < 16; ++c)
                acc[c] = fmaf(s, wr[c], acc[c]);
        }
        __syncthreads();
    }

    // combine split-K halves through LDS (reuse sx after barrier)
    float* part = sx;
    if (hf == 1) {
#pragma unroll
        for (int c = 0; c < 16; ++c) part[node * 17 + c] = acc[c];
    }
    __syncthreads();
    if (hf == 0) {
        int gn = node0 + node;
        if (gn < nN) {
#pragma unroll
            for (int c = 0; c < 16; ++c) acc[c] += part[node * 17 + c];
            float4* o = (float4*)(h1 + (size_t)gn * HID);
#pragma unroll
            for (int g = 0; g < 4; ++g)
                o[g] = make_float4(acc[g * 4 + 0], acc[g * 4 + 1],
                                   acc[g * 4 + 2], acc[g * 4 + 3]);
        }
    }
}

// ---------------- Bucket-level histogram (LDS-first, 2 edges/iter) ---------
__global__ __launch_bounds__(256) void bucket_hist_kernel(
    const void* __restrict__ eidx, int* __restrict__ bcnt, int nE)
{
    __shared__ int h[NBUCK];
    for (int i = threadIdx.x; i < NBUCK; i += 256) h[i] = 0;
    __syncthreads();
    const int i64 = g_idx64;
    int stride = gridDim.x * 256;
    int tid = blockIdx.x * 256 + threadIdx.x;
    if ((nE & 1) == 0) {
        int nE2 = nE >> 1;
        if (i64) {
            const int4* dp = (const int4*)((const long long*)eidx + nE);
            for (int i = tid; i < nE2; i += stride) {
                int4 d = dp[i];
                if (d.y == 0 && (unsigned)d.x < (unsigned)NN) atomicAdd(&h[d.x >> 8], 1);
                if (d.w == 0 && (unsigned)d.z < (unsigned)NN) atomicAdd(&h[d.z >> 8], 1);
            }
        } else {
            const int2* dp = (const int2*)((const int*)eidx + nE);
            for (int i = tid; i < nE2; i += stride) {
                int2 d = dp[i];
                if ((unsigned)d.x < (unsigned)NN) atomicAdd(&h[d.x >> 8], 1);
                if ((unsigned)d.y < (unsigned)NN) atomicAdd(&h[d.y >> 8], 1);
            }
        }
    } else {
        for (int e = tid; e < nE; e += stride) {
            int d;
            if (i64) d = (int)((const long long*)eidx)[nE + e];
            else     d = ((const int*)eidx)[nE + e];
            if ((unsigned)d < (unsigned)NN) atomicAdd(&h[d >> 8], 1);
        }
    }
    __syncthreads();
    for (int i = threadIdx.x; i < NBUCK; i += 256)
        if (h[i]) atomicAdd(&bcnt[i], h[i]);
}

// ---------------- Scan of 392 bucket counts -> bbase / cursor --------------
__global__ __launch_bounds__(512) void bucket_scan_kernel(
    const int* __restrict__ bcnt, int* __restrict__ bbase,
    int* __restrict__ cursor, int* __restrict__ rowStart)
{
    __shared__ int s[512];
    int t = threadIdx.x;
    int v = (t < NBUCK) ? bcnt[t] : 0;
    s[t] = v;
    __syncthreads();
    for (int off = 1; off < 512; off <<= 1) {
        int u = (t >= off) ? s[t - off] : 0;
        __syncthreads();
        s[t] += u;
        __syncthreads();
    }
    int excl = s[t] - v;   // exclusive prefix
    if (t < NBUCK) { bbase[t] = excl; cursor[t] = excl; }
    if (t == NBUCK) bbase[t] = excl;          // == total
    if (t == NBUCK) rowStart[NN] = excl;
}

// ---------------- Pass A: coarse bucket sort -------------------------------
__global__ __launch_bounds__(256) void bucketA_kernel(
    const void* __restrict__ eidx, const float* __restrict__ ew,
    int* __restrict__ cursor, int2* __restrict__ packed, int nE)
{
    __shared__ int cnt[NBUCK];
    __shared__ int base[NBUCK];
    int t = threadIdx.x;
    for (int i = t; i < NBUCK; i += 256) cnt[i] = 0;
    __syncthreads();

    const int e0 = blockIdx.x * EPB;
    const int i64 = g_idx64;
    int lo[16]; float wv[16]; int bk[16];
#pragma unroll
    for (int i = 0; i < 16; ++i) {
        int e = e0 + t + i * 256;
        bk[i] = -1;
        if (e < nE) {
            int s, d;
            if (i64) {
                const long long* p = (const long long*)eidx;
                s = (int)p[e]; d = (int)p[nE + e];
            } else {
                const int* p = (const int*)eidx;
                s = p[e]; d = p[nE + e];
            }
            if ((unsigned)d < (unsigned)NN) {
                float w = ew[e];
                if ((unsigned)s >= (unsigned)NN) { s = 0; w = 0.f; }
                bk[i] = d >> 8;
                lo[i] = s | ((d & 255) << 20);
                wv[i] = w;
                atomicAdd(&cnt[bk[i]], 1);
            }
        }
    }
    __syncthreads();
    for (int i = t; i < NBUCK; i += 256)
        base[i] = (cnt[i] > 0) ? atomicAdd(&cursor[i], cnt[i]) : 0;
    __syncthreads();
    for (int i = t; i < NBUCK; i += 256) cnt[i] = 0;
    __syncthreads();
#pragma unroll
    for (int i = 0; i < 16; ++i) {
        if (bk[i] >= 0) {
            int r = atomicAdd(&cnt[bk[i]], 1);
            packed[base[bk[i]] + r] = make_int2(lo[i], __float_as_int(wv[i]));
        }
    }
}

// ---------------- Pass B: per-bucket fine CSR, single global read ----------
__global__ __launch_bounds__(256) void bucketB_kernel(
    const int2* __restrict__ packed, const int* __restrict__ bbase,
    int* __restrict__ rowStart, int2* __restrict__ se, int nN)
{
    __shared__ int hcnt[256];
    __shared__ int wtot[4];
    __shared__ int2 stage[BCAP];
    int b = blockIdx.x;
    int t = threadIdx.x;
    int beg = bbase[b], end = bbase[b + 1];
    int cnt = end - beg;

    hcnt[t] = 0;
    __syncthreads();
    for (int i = t; i < cnt; i += 256) {
        int2 e = packed[beg + i];
        if (i < BCAP) stage[i] = e;
        atomicAdd(&hcnt[(e.x >> 20) & 255], 1);
    }
    __syncthreads();

    // exclusive scan of hcnt[256]: shfl within waves + wave offsets
    int v = hcnt[t];
    int incl = v;
#pragma unroll
    for (int off = 1; off < 64; off <<= 1) {
        int u = __shfl_up(incl, off, 64);
        if ((t & 63) >= off) incl += u;
    }
    if ((t & 63) == 63) wtot[t >> 6] = incl;
    __syncthreads();
    int woff = 0;
#pragma unroll
    for (int w = 0; w < 4; ++w) if (w < (t >> 6)) woff += wtot[w];
    int excl = incl - v + woff;

    int node = b * 256 + t;
    if (node < nN) rowStart[node] = beg + excl;
    __syncthreads();
    hcnt[t] = beg + excl;   // reuse as cursor
    __syncthreads();

    for (int i = t; i < cnt; i += 256) {
        int2 e = (i < BCAP) ? stage[i] : packed[beg + i];
        int dl = (e.x >> 20) & 255;
        int pos = atomicAdd(&hcnt[dl], 1);
        se[pos] = make_int2(e.x & 0xFFFFF, e.y);
    }
}

// ---------------- Fused aggregation ----------------------------------------
// agg[n] = sum_e w_e * h[src_e]; 4 threads per node (one float4 slice each).
// EPI==0: epilogue h2 = relu(agg + b1) @ Wn   (full 16-vec via quad shuffles)
// EPI==1: epilogue out = log_softmax(agg + b2)
template <int EPI>
__global__ __launch_bounds__(256) void gather_fused_kernel(
    const int* __restrict__ rowStart, const int2* __restrict__ se,
    const float* __restrict__ h, const float* __restrict__ bias,
    const float* __restrict__ Wn, float* __restrict__ outp, int nN)
{
    __shared__ float sW[256];
    __shared__ float sb[16];
    if (EPI == 0) sW[threadIdx.x] = Wn[threadIdx.x];
    if (threadIdx.x < 16) sb[threadIdx.x] = bias[threadIdx.x];
    __syncthreads();

    int t = blockIdx.x * 256 + threadIdx.x;
    int n = t >> 2;
    if (n >= nN) return;          // quad-uniform: n identical across the quad
    int c4 = t & 3;
    int beg = rowStart[n], end = rowStart[n + 1];
    const float4* h4 = (const float4*)h;

    float ax = 0.f, ay = 0.f, az = 0.f, aw = 0.f;
    int p = beg;
    // 4 independent load chains in flight per thread
    for (; p + 4 <= end; p += 4) {
        int2 e0 = se[p], e1 = se[p + 1], e2 = se[p + 2], e3 = se[p + 3];
        float4 v0 = h4[(size_t)(unsigned)e0.x * 4 + c4];
        float4 v1 = h4[(size_t)(unsigned)e1.x * 4 + c4];
        float4 v2 = h4[(size_t)(unsigned)e2.x * 4 + c4];
        float4 v3 = h4[(size_t)(unsigned)e3.x * 4 + c4];
        float w0 = __int_as_float(e0.y), w1 = __int_as_float(e1.y);
        float w2 = __int_as_float(e2.y), w3 = __int_as_float(e3.y);
        ax = fmaf(w0, v0.x, ax); ay = fmaf(w0, v0.y, ay);
        az = fmaf(w0, v0.z, az); aw = fmaf(w0, v0.w, aw);
        ax = fmaf(w1, v1.x, ax); ay = fmaf(w1, v1.y, ay);
        az = fmaf(w1, v1.z, az); aw = fmaf(w1, v1.w, aw);
        ax = fmaf(w2, v2.x, ax); ay = fmaf(w2, v2.y, ay);
        az = fmaf(w2, v2.z, az); aw = fmaf(w2, v2.w, aw);
        ax = fmaf(w3, v3.x, ax); ay = fmaf(w3, v3.y, ay);
        az = fmaf(w3, v3.z, az); aw = fmaf(w3, v3.w, aw);
    }
    for (; p < end; ++p) {
        int2 e = se[p];
        float4 v = h4[(size_t)(unsigned)e.x * 4 + c4];
        float w = __int_as_float(e.y);
        ax = fmaf(w, v.x, ax); ay = fmaf(w, v.y, ay);
        az = fmaf(w, v.z, az); aw = fmaf(w, v.w, aw);
    }

    int lane = threadIdx.x & 63;
    int lb = lane & ~3;           // quad base lane

    if (EPI == 0) {
        float v0 = fmaxf(ax + sb[c4 * 4 + 0], 0.f);
        float v1 = fmaxf(ay + sb[c4 * 4 + 1], 0.f);
        float v2 = fmaxf(az + sb[c4 * 4 + 2], 0.f);
        float v3 = fmaxf(aw + sb[c4 * 4 + 3], 0.f);
        float vk[16];
#pragma unroll
        for (int j = 0; j < 4; ++j) {
            vk[4 * j + 0] = __shfl(v0, lb + j, 64);
            vk[4 * j + 1] = __shfl(v1, lb + j, 64);
            vk[4 * j + 2] = __shfl(v2, lb + j, 64);
            vk[4 * j + 3] = __shfl(v3, lb + j, 64);
        }
        float o0 = 0.f, o1 = 0.f, o2 = 0.f, o3 = 0.f;
#pragma unroll
        for (int k = 0; k < 16; ++k) {
            float s = vk[k];
            o0 = fmaf(s, sW[k * 16 + c4 * 4 + 0], o0);
            o1 = fmaf(s, sW[k * 16 + c4 * 4 + 1], o1);
            o2 = fmaf(s, sW[k * 16 + c4 * 4 + 2], o2);
            o3 = fmaf(s, sW[k * 16 + c4 * 4 + 3], o3);
        }
        ((float4*)outp)[(size_t)n * 4 + c4] = make_float4(o0, o1, o2, o3);
    } else {
        float v0 = ax + sb[c4 * 4 + 0];
        float v1 = ay + sb[c4 * 4 + 1];
        float v2 = az + sb[c4 * 4 + 2];
        float v3 = aw + sb[c4 * 4 + 3];
        float m = fmaxf(fmaxf(v0, v1), fmaxf(v2, v3));
        m = fmaxf(m, __shfl_xor(m, 1, 64));
        m = fmaxf(m, __shfl_xor(m, 2, 64));
        float s = expf(v0 - m) + expf(v1 - m) + expf(v2 - m) + expf(v3 - m);
        s += __shfl_xor(s, 1, 64);
        s += __shfl_xor(s, 2, 64);
        float l = m + logf(s);
        ((float4*)outp)[(size_t)n * 4 + c4] =
            make_float4(v0 - l, v1 - l, v2 - l, v3 - l);
    }
}

extern "C" void kernel_launch(void* const* d_in, const int* in_sizes, int n_in,
                              void* d_out, int out_size, void* d_ws, size_t ws_size,
                              hipStream_t stream)
{
    const float* x  = (const float*)d_in[0];
    const void*  ei = d_in[1];
    const float* ew = (const float*)d_in[2];
    const float* W1 = (const float*)d_in[3];
    const float* b1 = (const float*)d_in[4];
    const float* W2 = (const float*)d_in[5];
    const float* b2 = (const float*)d_in[6];
    float* out = (float*)d_out;

    const int N = NN;
    const int E = in_sizes[2];

    const size_t featB = (size_t)N * HID * sizeof(float);           // 6.4 MB
    const size_t rowB  = (((size_t)(N + 1) * 4) + 255) & ~255ULL;
    const size_t bkB   = (((size_t)(NBUCK + 1) * 4) + 255) & ~255ULL;
    const size_t seB   = ((size_t)E * 8 + 255) & ~255ULL;           // 25.6 MB

    char* w = (char*)d_ws;
    float* buf0 = (float*)w;      w += (featB + 255) & ~255ULL;
    float* buf1 = (float*)w;      w += (featB + 255) & ~255ULL;
    int*   rowStart = (int*)w;    w += rowB;
    int*   bcnt = (int*)w;        w += bkB;
    int*   bbase = (int*)w;       w += bkB;
    int*   cursor = (int*)w;      w += bkB;
    int2*  se = (int2*)w;         w += seB;
    int2*  packed = (int2*)w;     w += seB;

    detect_idx_kernel<<<1, 64, 0, stream>>>((const long long*)ei);
    gemm1_kernel<<<(N + TN - 1) / TN, 512, 0, stream>>>(x, W1, buf0, N);

    const int nblocks4 = (N * 4 + 255) / 256;

    // Bucketed CSR build: LDS-first histogram, tiny scan, per-bucket fine CSR.
    hipMemsetAsync(bcnt, 0, (size_t)NBUCK * 4, stream);
    bucket_hist_kernel<<<256, 256, 0, stream>>>(ei, bcnt, E);
    bucket_scan_kernel<<<1, 512, 0, stream>>>(bcnt, bbase, cursor, rowStart);
    bucketA_kernel<<<(E + EPB - 1) / EPB, 256, 0, stream>>>(ei, ew, cursor, packed, E);
    bucketB_kernel<<<NBUCK, 256, 0, stream>>>(packed, bbase, rowStart, se, N);

    // Fused: gather+transform (h2 = relu(agg1+b1)@W2), gather+log_softmax.
    gather_fused_kernel<0><<<nblocks4, 256, 0, stream>>>(rowStart, se, buf0, b1, W2, buf1, N);
    gather_fused_kernel<1><<<nblocks4, 256, 0, stream>>>(rowStart, se, buf1, b2, W2, out, N);
}

// Round 5
// 502.817 us; speedup vs baseline: 1.2200x; 1.0098x over previous
//
#include <hip/hip_runtime.h>
#include <math.h>

#define NN 100000
#define DF 512
#define HID 16
#define NBUCK 392            // ceil(NN/256) buckets of 256 dst values
#define EPB 4096             // edges per block in bucketA (256 thr x 16)
#define BCAP 7800            // bucketB LDS staging capacity (62.4 KB)

#define TN 256               // gemm1: nodes per block
#define KC 64                // gemm1: k-chunk (floats)
#define NCH (DF / KC)        // 8 chunks
#define LROW 65              // padded LDS row stride: bank = node%32 -> 2-way = free

// Flag: 1 if edge_index is int64-laid-out, 0 if int32.
__device__ int g_idx64;

__global__ void detect_idx_kernel(const long long* __restrict__ idx) {
    int lane = threadIdx.x;  // 64 threads
    int ok = 1;
    for (int i = lane; i < 128; i += 64) {
        long long v = idx[i];
        if (v < 0 || v >= NN) ok = 0;
    }
    unsigned long long m = __ballot(ok);
    if (lane == 0) g_idx64 = (m == ~0ULL);
}

// ---------------- GEMM1: h1 = x @ W1 ---------------------------------------
// 512 threads / 256-node tile. x staged through LDS with 256B-contiguous
// coalesced loads; +1-padded rows keep LDS at 2 lanes/bank (free). W1 on the
// scalar path via hf = readfirstlane(t>>8) (round-4 confirmed: divergent W1
// addressing was the 190us regression). NEW: two-deep register prefetch
// (pfA/pfB, fully unrolled loop so indices are compile-time) -> 16
// outstanding 16B loads/thread to cover HBM latency.
__global__ __launch_bounds__(512) void gemm1_kernel(
    const float* __restrict__ x, const float* __restrict__ W1,
    float* __restrict__ h1, int nN)
{
    __shared__ float sx[TN * LROW];      // 66.6 KB; reused for combine
    const int t = threadIdx.x;
    const int hf = __builtin_amdgcn_readfirstlane(t >> 8);  // waves 0-3: 0, 4-7: 1
    const int node = t & (TN - 1);
    const int node0 = blockIdx.x * TN;
    const int tr = t >> 4;               // 0..31: row-in-pass for staging
    const int tq = t & 15;               // 0..15: float4 col for staging

    const float4* x4 = (const float4*)x;
    int rowg[8];
#pragma unroll
    for (int i = 0; i < 8; ++i) {
        int r = node0 + i * 32 + tr;
        rowg[i] = (r < nN) ? r : (nN - 1);   // clamp: duplicate loads, harmless
    }

    float acc[16];
#pragma unroll
    for (int c = 0; c < 16; ++c) acc[c] = 0.f;

    float4 pfA[8], pfB[8];

    auto issue = [&](float4* buf, int kc) {
#pragma unroll
        for (int i = 0; i < 8; ++i)
            buf[i] = x4[(size_t)rowg[i] * (DF / 4) + kc * 16 + tq];
    };
    auto step = [&](float4* buf, int kc) {
        // stage chunk kc into LDS (compiler inserts vmcnt waits on buf use)
#pragma unroll
        for (int i = 0; i < 8; ++i) {
            int a = (i * 32 + tr) * LROW + tq * 4;
            sx[a + 0] = buf[i].x; sx[a + 1] = buf[i].y;
            sx[a + 2] = buf[i].z; sx[a + 3] = buf[i].w;
        }
        __syncthreads();
        // refill this buffer two chunks ahead; flies during compute
        if (kc + 2 < NCH) issue(buf, kc + 2);
        const float* wb = W1 + (kc * KC + hf * 32) * HID;  // uniform -> s_load
        const float* xr = sx + node * LROW + hf * 32;
#pragma unroll 4
        for (int kk = 0; kk < 32; ++kk) {
            float s = xr[kk];
            const float* wr = wb + kk * HID;
#pragma unroll
            for (int c = 0; c < 16; ++c)
                acc[c] = fmaf(s, wr[c], acc[c]);
        }
        __syncthreads();
    };

    issue(pfA, 0);
    issue(pfB, 1);
#pragma unroll
    for (int kc2 = 0; kc2 < NCH; kc2 += 2) {
        step(pfA, kc2);
        step(pfB, kc2 + 1);
    }

    // combine split-K halves through LDS (reuse sx after barrier)
    float* part = sx;
    if (hf == 1) {
#pragma unroll
        for (int c = 0; c < 16; ++c) part[node * 17 + c] = acc[c];
    }
    __syncthreads();
    if (hf == 0) {
        int gn = node0 + node;
        if (gn < nN) {
#pragma unroll
            for (int c = 0; c < 16; ++c) acc[c] += part[node * 17 + c];
            float4* o = (float4*)(h1 + (size_t)gn * HID);
#pragma unroll
            for (int g = 0; g < 4; ++g)
                o[g] = make_float4(acc[g * 4 + 0], acc[g * 4 + 1],
                                   acc[g * 4 + 2], acc[g * 4 + 3]);
        }
    }
}

// ---------------- Bucket-level histogram (LDS-first, 2 edges/iter) ---------
__global__ __launch_bounds__(256) void bucket_hist_kernel(
    const void* __restrict__ eidx, int* __restrict__ bcnt, int nE)
{
    __shared__ int h[NBUCK];
    for (int i = threadIdx.x; i < NBUCK; i += 256) h[i] = 0;
    __syncthreads();
    const int i64 = g_idx64;
    int stride = gridDim.x * 256;
    int tid = blockIdx.x * 256 + threadIdx.x;
    if ((nE & 1) == 0) {
        int nE2 = nE >> 1;
        if (i64) {
            const int4* dp = (const int4*)((const long long*)eidx + nE);
            for (int i = tid; i < nE2; i += stride) {
                int4 d = dp[i];
                if (d.y == 0 && (unsigned)d.x < (unsigned)NN) atomicAdd(&h[d.x >> 8], 1);
                if (d.w == 0 && (unsigned)d.z < (unsigned)NN) atomicAdd(&h[d.z >> 8], 1);
            }
        } else {
            const int2* dp = (const int2*)((const int*)eidx + nE);
            for (int i = tid; i < nE2; i += stride) {
                int2 d = dp[i];
                if ((unsigned)d.x < (unsigned)NN) atomicAdd(&h[d.x >> 8], 1);
                if ((unsigned)d.y < (unsigned)NN) atomicAdd(&h[d.y >> 8], 1);
            }
        }
    } else {
        for (int e = tid; e < nE; e += stride) {
            int d;
            if (i64) d = (int)((const long long*)eidx)[nE + e];
            else     d = ((const int*)eidx)[nE + e];
            if ((unsigned)d < (unsigned)NN) atomicAdd(&h[d >> 8], 1);
        }
    }
    __syncthreads();
    for (int i = threadIdx.x; i < NBUCK; i += 256)
        if (h[i]) atomicAdd(&bcnt[i], h[i]);
}

// ---------------- Scan of 392 bucket counts -> bbase / cursor --------------
__global__ __launch_bounds__(512) void bucket_scan_kernel(
    const int* __restrict__ bcnt, int* __restrict__ bbase,
    int* __restrict__ cursor, int* __restrict__ rowStart)
{
    __shared__ int s[512];
    int t = threadIdx.x;
    int v = (t < NBUCK) ? bcnt[t] : 0;
    s[t] = v;
    __syncthreads();
    for (int off = 1; off < 512; off <<= 1) {
        int u = (t >= off) ? s[t - off] : 0;
        __syncthreads();
        s[t] += u;
        __syncthreads();
    }
    int excl = s[t] - v;   // exclusive prefix
    if (t < NBUCK) { bbase[t] = excl; cursor[t] = excl; }
    if (t == NBUCK) bbase[t] = excl;          // == total
    if (t == NBUCK) rowStart[NN] = excl;
}

// ---------------- Pass A: coarse bucket sort -------------------------------
__global__ __launch_bounds__(256) void bucketA_kernel(
    const void* __restrict__ eidx, const float* __restrict__ ew,
    int* __restrict__ cursor, int2* __restrict__ packed, int nE)
{
    __shared__ int cnt[NBUCK];
    __shared__ int base[NBUCK];
    int t = threadIdx.x;
    for (int i = t; i < NBUCK; i += 256) cnt[i] = 0;
    __syncthreads();

    const int e0 = blockIdx.x * EPB;
    const int i64 = g_idx64;
    int lo[16]; float wv[16]; int bk[16];
#pragma unroll
    for (int i = 0; i < 16; ++i) {
        int e = e0 + t + i * 256;
        bk[i] = -1;
        if (e < nE) {
            int s, d;
            if (i64) {
                const long long* p = (const long long*)eidx;
                s = (int)p[e]; d = (int)p[nE + e];
            } else {
                const int* p = (const int*)eidx;
                s = p[e]; d = p[nE + e];
            }
            if ((unsigned)d < (unsigned)NN) {
                float w = ew[e];
                if ((unsigned)s >= (unsigned)NN) { s = 0; w = 0.f; }
                bk[i] = d >> 8;
                lo[i] = s | ((d & 255) << 20);
                wv[i] = w;
                atomicAdd(&cnt[bk[i]], 1);
            }
        }
    }
    __syncthreads();
    for (int i = t; i < NBUCK; i += 256)
        base[i] = (cnt[i] > 0) ? atomicAdd(&cursor[i], cnt[i]) : 0;
    __syncthreads();
    for (int i = t; i < NBUCK; i += 256) cnt[i] = 0;
    __syncthreads();
#pragma unroll
    for (int i = 0; i < 16; ++i) {
        if (bk[i] >= 0) {
            int r = atomicAdd(&cnt[bk[i]], 1);
            packed[base[bk[i]] + r] = make_int2(lo[i], __float_as_int(wv[i]));
        }
    }
}

// ---------------- Pass B: per-bucket fine CSR, single global read ----------
__global__ __launch_bounds__(256) void bucketB_kernel(
    const int2* __restrict__ packed, const int* __restrict__ bbase,
    int* __restrict__ rowStart, int2* __restrict__ se, int nN)
{
    __shared__ int hcnt[256];
    __shared__ int wtot[4];
    __shared__ int2 stage[BCAP];
    int b = blockIdx.x;
    int t = threadIdx.x;
    int beg = bbase[b], end = bbase[b + 1];
    int cnt = end - beg;

    hcnt[t] = 0;
    __syncthreads();
    for (int i = t; i < cnt; i += 256) {
        int2 e = packed[beg + i];
        if (i < BCAP) stage[i] = e;
        atomicAdd(&hcnt[(e.x >> 20) & 255], 1);
    }
    __syncthreads();

    // exclusive scan of hcnt[256]: shfl within waves + wave offsets
    int v = hcnt[t];
    int incl = v;
#pragma unroll
    for (int off = 1; off < 64; off <<= 1) {
        int u = __shfl_up(incl, off, 64);
        if ((t & 63) >= off) incl += u;
    }
    if ((t & 63) == 63) wtot[t >> 6] = incl;
    __syncthreads();
    int woff = 0;
#pragma unroll
    for (int w = 0; w < 4; ++w) if (w < (t >> 6)) woff += wtot[w];
    int excl = incl - v + woff;

    int node = b * 256 + t;
    if (node < nN) rowStart[node] = beg + excl;
    __syncthreads();
    hcnt[t] = beg + excl;   // reuse as cursor
    __syncthreads();

    for (int i = t; i < cnt; i += 256) {
        int2 e = (i < BCAP) ? stage[i] : packed[beg + i];
        int dl = (e.x >> 20) & 255;
        int pos = atomicAdd(&hcnt[dl], 1);
        se[pos] = make_int2(e.x & 0xFFFFF, e.y);
    }
}

// ---------------- Fused aggregation ----------------------------------------
// agg[n] = sum_e w_e * h[src_e]; 4 threads per node (one float4 slice each).
// 8-wide unrolled main loop: 8 independent se+h load chains in flight.
// EPI==0: epilogue h2 = relu(agg + b1) @ Wn   (full 16-vec via quad shuffles)
// EPI==1: epilogue out = log_softmax(agg + b2)
template <int EPI>
__global__ __launch_bounds__(256) void gather_fused_kernel(
    const int* __restrict__ rowStart, const int2* __restrict__ se,
    const float* __restrict__ h, const float* __restrict__ bias,
    const float* __restrict__ Wn, float* __restrict__ outp, int nN)
{
    __shared__ float sW[256];
    __shared__ float sb[16];
    if (EPI == 0) sW[threadIdx.x] = Wn[threadIdx.x];
    if (threadIdx.x < 16) sb[threadIdx.x] = bias[threadIdx.x];
    __syncthreads();

    int t = blockIdx.x * 256 + threadIdx.x;
    int n = t >> 2;
    if (n >= nN) return;          // quad-uniform: n identical across the quad
    int c4 = t & 3;
    int beg = rowStart[n], end = rowStart[n + 1];
    const float4* h4 = (const float4*)h;

    float ax = 0.f, ay = 0.f, az = 0.f, aw = 0.f;
    int p = beg;
    // 8 independent load chains in flight per thread
    for (; p + 8 <= end; p += 8) {
        int2 ee[8];
        float4 vv[8];
#pragma unroll
        for (int j = 0; j < 8; ++j) ee[j] = se[p + j];
#pragma unroll
        for (int j = 0; j < 8; ++j)
            vv[j] = h4[(size_t)(unsigned)ee[j].x * 4 + c4];
#pragma unroll
        for (int j = 0; j < 8; ++j) {
            float w = __int_as_float(ee[j].y);
            ax = fmaf(w, vv[j].x, ax); ay = fmaf(w, vv[j].y, ay);
            az = fmaf(w, vv[j].z, az); aw = fmaf(w, vv[j].w, aw);
        }
    }
    if (p + 4 <= end) {
        int2 ee[4];
        float4 vv[4];
#pragma unroll
        for (int j = 0; j < 4; ++j) ee[j] = se[p + j];
#pragma unroll
        for (int j = 0; j < 4; ++j)
            vv[j] = h4[(size_t)(unsigned)ee[j].x * 4 + c4];
#pragma unroll
        for (int j = 0; j < 4; ++j) {
            float w = __int_as_float(ee[j].y);
            ax = fmaf(w, vv[j].x, ax); ay = fmaf(w, vv[j].y, ay);
            az = fmaf(w, vv[j].z, az); aw = fmaf(w, vv[j].w, aw);
        }
        p += 4;
    }
    for (; p < end; ++p) {
        int2 e = se[p];
        float4 v = h4[(size_t)(unsigned)e.x * 4 + c4];
        float w = __int_as_float(e.y);
        ax = fmaf(w, v.x, ax); ay = fmaf(w, v.y, ay);
        az = fmaf(w, v.z, az); aw = fmaf(w, v.w, aw);
    }

    int lane = threadIdx.x & 63;
    int lb = lane & ~3;           // quad base lane

    if (EPI == 0) {
        float v0 = fmaxf(ax + sb[c4 * 4 + 0], 0.f);
        float v1 = fmaxf(ay + sb[c4 * 4 + 1], 0.f);
        float v2 = fmaxf(az + sb[c4 * 4 + 2], 0.f);
        float v3 = fmaxf(aw + sb[c4 * 4 + 3], 0.f);
        float vk[16];
#pragma unroll
        for (int j = 0; j < 4; ++j) {
            vk[4 * j + 0] = __shfl(v0, lb + j, 64);
            vk[4 * j + 1] = __shfl(v1, lb + j, 64);
            vk[4 * j + 2] = __shfl(v2, lb + j, 64);
            vk[4 * j + 3] = __shfl(v3, lb + j, 64);
        }
        float o0 = 0.f, o1 = 0.f, o2 = 0.f, o3 = 0.f;
#pragma unroll
        for (int k = 0; k < 16; ++k) {
            float s = vk[k];
            o0 = fmaf(s, sW[k * 16 + c4 * 4 + 0], o0);
            o1 = fmaf(s, sW[k * 16 + c4 * 4 + 1], o1);
            o2 = fmaf(s, sW[k * 16 + c4 * 4 + 2], o2);
            o3 = fmaf(s, sW[k * 16 + c4 * 4 + 3], o3);
        }
        ((float4*)outp)[(size_t)n * 4 + c4] = make_float4(o0, o1, o2, o3);
    } else {
        float v0 = ax + sb[c4 * 4 + 0];
        float v1 = ay + sb[c4 * 4 + 1];
        float v2 = az + sb[c4 * 4 + 2];
        float v3 = aw + sb[c4 * 4 + 3];
        float m = fmaxf(fmaxf(v0, v1), fmaxf(v2, v3));
        m = fmaxf(m, __shfl_xor(m, 1, 64));
        m = fmaxf(m, __shfl_xor(m, 2, 64));
        float s = expf(v0 - m) + expf(v1 - m) + expf(v2 - m) + expf(v3 - m);
        s += __shfl_xor(s, 1, 64);
        s += __shfl_xor(s, 2, 64);
        float l = m + logf(s);
        ((float4*)outp)[(size_t)n * 4 + c4] =
            make_float4(v0 - l, v1 - l, v2 - l, v3 - l);
    }
}

extern "C" void kernel_launch(void* const* d_in, const int* in_sizes, int n_in,
                              void* d_out, int out_size, void* d_ws, size_t ws_size,
                              hipStream_t stream)
{
    const float* x  = (const float*)d_in[0];
    const void*  ei = d_in[1];
    const float* ew = (const float*)d_in[2];
    const float* W1 = (const float*)d_in[3];
    const float* b1 = (const float*)d_in[4];
    const float* W2 = (const float*)d_in[5];
    const float* b2 = (const float*)d_in[6];
    float* out = (float*)d_out;

    const int N = NN;
    const int E = in_sizes[2];

    const size_t featB = (size_t)N * HID * sizeof(float);           // 6.4 MB
    const size_t rowB  = (((size_t)(N + 1) * 4) + 255) & ~255ULL;
    const size_t bkB   = (((size_t)(NBUCK + 1) * 4) + 255) & ~255ULL;
    const size_t seB   = ((size_t)E * 8 + 255) & ~255ULL;           // 25.6 MB

    char* w = (char*)d_ws;
    float* buf0 = (float*)w;      w += (featB + 255) & ~255ULL;
    float* buf1 = (float*)w;      w += (featB + 255) & ~255ULL;
    int*   rowStart = (int*)w;    w += rowB;
    int*   bcnt = (int*)w;        w += bkB;
    int*   bbase = (int*)w;       w += bkB;
    int*   cursor = (int*)w;      w += bkB;
    int2*  se = (int2*)w;         w += seB;
    int2*  packed = (int2*)w;     w += seB;

    detect_idx_kernel<<<1, 64, 0, stream>>>((const long long*)ei);
    gemm1_kernel<<<(N + TN - 1) / TN, 512, 0, stream>>>(x, W1, buf0, N);

    const int nblocks4 = (N * 4 + 255) / 256;

    // Bucketed CSR build: LDS-first histogram, tiny scan, per-bucket fine CSR.
    hipMemsetAsync(bcnt, 0, (size_t)NBUCK * 4, stream);
    bucket_hist_kernel<<<256, 256, 0, stream>>>(ei, bcnt, E);
    bucket_scan_kernel<<<1, 512, 0, stream>>>(bcnt, bbase, cursor, rowStart);
    bucketA_kernel<<<(E + EPB - 1) / EPB, 256, 0, stream>>>(ei, ew, cursor, packed, E);
    bucketB_kernel<<<NBUCK, 256, 0, stream>>>(packed, bbase, rowStart, se, N);

    // Fused: gather+transform (h2 = relu(agg1+b1)@W2), gather+log_softmax.
    gather_fused_kernel<0><<<nblocks4, 256, 0, stream>>>(rowStart, se, buf0, b1, W2, buf1, N);
    gather_fused_kernel<1><<<nblocks4, 256, 0, stream>>>(rowStart, se, buf1, b2, W2, out, N);
}